// Round 9
// baseline (240.209 us; speedup 1.0000x reference)
//
#include <hip/hip_runtime.h>
#include <hip/hip_bf16.h>
#include <math.h>

constexpr int B_ = 2;
constexpr int N_ = 1024;
constexpr int D_ = 256;
constexpr int H_ = 8;
constexpr int DH_ = 32;
constexpr float SCALE_ = 0.17677669529663687f;  // 1/sqrt(32)
constexpr float LOG2E_ = 1.4426950408889634f;
constexpr float SCALE2_ = SCALE_ * LOG2E_;      // qk scale in exp2 domain
constexpr float EPSV_ = 1e-4f;
constexpr unsigned GRID_ = 512;

typedef __attribute__((ext_vector_type(8))) short short8;
typedef __attribute__((ext_vector_type(4))) float f32x4;
typedef __attribute__((ext_vector_type(2))) float f32x2;

__device__ __forceinline__ unsigned short f2bf(float x) {
  __hip_bfloat16 h = __float2bfloat16(x);
  return __builtin_bit_cast(unsigned short, h);
}
__device__ __forceinline__ float bf2f(unsigned short u) {
  unsigned int x = ((unsigned int)u) << 16;
  return __builtin_bit_cast(float, x);
}
__device__ __forceinline__ f32x2 max2(f32x2 a, f32x2 b) {
  return __builtin_elementwise_max(a, b);
}

__device__ __forceinline__ float lgamma_fast(float x) {
  float y = (x < 1.f) ? x : (x - 1.f);
  float g = fmaf(y, 0.035868343f, -0.193527818f);
  g = fmaf(y, g, 0.482199394f);
  g = fmaf(y, g, -0.756704078f);
  g = fmaf(y, g, 0.918206857f);
  g = fmaf(y, g, -0.897056937f);
  g = fmaf(y, g, 0.988205891f);
  g = fmaf(y, g, -0.577191652f);
  g = fmaf(y, g, 1.0f);
  float lg = __logf(g);
  return (x < 1.f) ? lg - __logf(x) : lg;
}
__device__ __forceinline__ float softplus_fast(float x) {
  return __logf(1.f + __expf(x));
}

// ---------------------------------------------------------------------------
// Device-scope grid barrier (Guideline-16 pattern: threadfence + device atomics
// handle cross-XCD L2 non-coherence). Counters zeroed by host-side async memset
// each launch. All GRID_ blocks are co-resident by construction (see launch).
// ---------------------------------------------------------------------------
__device__ __forceinline__ void grid_barrier(unsigned* bar, int idx) {
  __syncthreads();
  if (threadIdx.x == 0) {
    __threadfence();                       // release: flush writes device-wide
    unsigned* cnt = bar + idx * 2;
    unsigned* flg = bar + idx * 2 + 1;
    unsigned old = atomicAdd(cnt, 1u);
    if (old == GRID_ - 1) {
      atomicExch(flg, 1u);                 // last block releases everyone
    } else {
      while (atomicAdd(flg, 0u) == 0u)     // device-scope atomic read
        __builtin_amdgcn_s_sleep(2);
    }
    __threadfence();                       // acquire: invalidate stale caches
  }
  __syncthreads();
}

// ---------------------------------------------------------------------------
// Pure-load split-bf16 MFMA GEMM wave body. C[16 rows][64 cols] per wave.
// acc row = (l>>4)*4 + reg, col = ct*16 + (l&15)  [m89/m91 layout].
// ---------------------------------------------------------------------------
__device__ __forceinline__
void mfma_wave_pure(const unsigned short* __restrict__ Ahi,
                    const unsigned short* __restrict__ Alo,
                    const unsigned short* __restrict__ whi,
                    const unsigned short* __restrict__ wlo,
                    int r0, int c0, int l, f32x4 (&acc)[4]) {
  const int lr = l & 15, lg = l >> 4;
#pragma unroll
  for (int ct = 0; ct < 4; ++ct) acc[ct] = (f32x4){0.f, 0.f, 0.f, 0.f};
#pragma unroll 2
  for (int ks = 0; ks < 8; ++ks) {
    size_t aoff = (size_t)(r0 + lr) * D_ + ks * 32 + lg * 8;
    short8 ahi = *(const short8*)(Ahi + aoff);
    short8 alo = *(const short8*)(Alo + aoff);
#pragma unroll
    for (int ct = 0; ct < 4; ++ct) {
      size_t woff = (size_t)(c0 + ct * 16 + lr) * D_ + ks * 32 + lg * 8;
      short8 wh = *(const short8*)(whi + woff);
      short8 wl = *(const short8*)(wlo + woff);
      acc[ct] = __builtin_amdgcn_mfma_f32_16x16x32_bf16(ahi, wh, acc[ct], 0, 0, 0);
      acc[ct] = __builtin_amdgcn_mfma_f32_16x16x32_bf16(alo, wh, acc[ct], 0, 0, 0);
      acc[ct] = __builtin_amdgcn_mfma_f32_16x16x32_bf16(ahi, wl, acc[ct], 0, 0, 0);
    }
  }
}

// ---------------------------------------------------------------------------
// ONE fused kernel, 512 blocks x 512 threads, 4 grid-barrier-separated phases:
//  P1: W/src hi-lo split (blocks 0..95 extra duty) + pair-bias (all blocks)
//  P2: QKV projections (blocks 0..191)
//  P3: flash attention (all blocks)
//  P4: output projection (blocks 0..63)
// Co-residency: __launch_bounds__(512,4) caps VGPR at 128 -> 16 waves/CU ->
// exactly 2 blocks/CU x 256 CU = 512 resident blocks. LDS 31KB*2 = 62KB/CU ok.
// ---------------------------------------------------------------------------
__global__ __launch_bounds__(512, 4)
void fused_kernel(const float* __restrict__ src, const float* __restrict__ coords,
                  const float* __restrict__ Wq, const float* __restrict__ Wk,
                  const float* __restrict__ Wv, const float* __restrict__ Wo,
                  const float* __restrict__ gw1, const float* __restrict__ gb1,
                  const float* __restrict__ gw2, const float* __restrict__ gb2,
                  const float* __restrict__ dw1, const float* __restrict__ db1,
                  const float* __restrict__ dw2, const float* __restrict__ db2,
                  float* __restrict__ out,
                  unsigned short* __restrict__ qbf, unsigned short* __restrict__ kbf,
                  unsigned short* __restrict__ vtbf, float* __restrict__ biasw,
                  unsigned short* __restrict__ whi, unsigned short* __restrict__ wlo,
                  unsigned short* __restrict__ shi, unsigned short* __restrict__ slo,
                  unsigned short* __restrict__ ophi, unsigned short* __restrict__ oplo,
                  unsigned* __restrict__ bar) {
  __shared__ __align__(16) unsigned short p_lds[8][16][72];
  __shared__ float acc_lds[3][2][16][32];
  __shared__ float ml_lds[3][2][16][2];

  const int t = threadIdx.x;
  const int bi = blockIdx.x;

  // ================= Phase 1: split (first 96 blocks) + bias (all) =========
  {
    int g = bi * 512 + t;
    if (g < 49152) {                       // 49152 threads x 16 floats = 768K
      int idx = g * 16;
      const float* p;
      unsigned short *dhi, *dlo;
      if (idx < 262144) {                  // W tables
        int m = idx >> 16;
        int off = idx & 65535;
        p = (m == 0) ? Wq : (m == 1) ? Wk : (m == 2) ? Wv : Wo;
        p += off;
        dhi = whi + idx; dlo = wlo + idx;
      } else {                             // src
        int off = idx - 262144;
        p = src + off;
        dhi = shi + off; dlo = slo + off;
      }
#pragma unroll
      for (int q = 0; q < 4; ++q) {
        float4 f = *(const float4*)(p + q * 4);
        ushort4 hi, lo;
        hi.x = f2bf(f.x); lo.x = f2bf(f.x - bf2f(hi.x));
        hi.y = f2bf(f.y); lo.y = f2bf(f.y - bf2f(hi.y));
        hi.z = f2bf(f.z); lo.z = f2bf(f.z - bf2f(hi.z));
        hi.w = f2bf(f.w); lo.w = f2bf(f.w - bf2f(hi.w));
        *(ushort4*)(dhi + q * 4) = hi;
        *(ushort4*)(dlo + q * 4) = lo;
      }
    }

    // bias: unit u = bi*2 + (t>=256), 1024 units of 256 threads
    const int u = bi * 2 + (t >> 8);
    const int utid = t & 255;
    const int jt = u & 3;
    const int it = (u >> 2) & 127;
    const int b  = u >> 9;
    const int j  = jt * 256 + utid;
    const int ibase = it * 8;

    const float4 cj = ((const float4*)coords)[b * N_ + j];
    f32x2 dist2[4], dtv2[4];
#pragma unroll
    for (int q = 0; q < 4; ++q) {
#pragma unroll
      for (int e = 0; e < 2; ++e) {
        const float* cp = coords + 4 * (b * N_ + ibase + q * 2 + e);
        float dx = cp[0] - cj.x, dy = cp[1] - cj.y, dz = cp[2] - cj.z;
        dist2[q][e] = sqrtf(dx * dx + dy * dy + dz * dz);
        dtv2[q][e]  = cp[3] - cj.w;
      }
    }

    const float db20 = db2[0], db21 = db2[1], gb20 = gb2[0];
    f32x2 bias2[4], r02[4], r12[4];
#pragma unroll
    for (int q = 0; q < 4; ++q) {
      bias2[q] = (f32x2){0.f, 0.f};
      r02[q]   = (f32x2){db20, db20};
      r12[q]   = (f32x2){db21, db21};
    }

#pragma unroll 4
    for (int h = 0; h < 64; ++h) {
      float g0 = gw1[2 * h], g1 = gw1[2 * h + 1], gb = gb1[h], g2 = gw2[h];
      float w0 = dw1[4 * h], wx = dw1[4 * h + 1], wy = dw1[4 * h + 2], wz = dw1[4 * h + 3];
      float c0 = db1[h], c1 = dw2[h], c2 = dw2[64 + h];
      float dp = fmaf(wx, cj.x, fmaf(wy, cj.y, fmaf(wz, cj.z, c0)));
      f32x2 g0v = {g0, g0}, g1v = {g1, g1}, gbv = {gb, gb}, g2v = {g2, g2};
      f32x2 w0v = {w0, w0}, dpv = {dp, dp}, c1v = {c1, c1}, c2v = {c2, c2};
      const f32x2 zero = {0.f, 0.f};
#pragma unroll
      for (int q = 0; q < 4; ++q) {
        f32x2 g = g0v * dist2[q] + g1v * dtv2[q] + gbv;
        bias2[q] += g2v * max2(g, zero);
        f32x2 dhv = max2(w0v * dist2[q] + dpv, zero);
        r02[q] += c1v * dhv;
        r12[q] += c2v * dhv;
      }
    }

#pragma unroll
    for (int ii = 0; ii < 8; ++ii) {
      int q = ii >> 1, e = ii & 1;
      float sh  = softplus_fast(r02[q][e]) + EPSV_;
      float ra  = softplus_fast(r12[q][e]) + EPSV_;
      float dtp = fmaxf(fabsf(dtv2[q][e]), EPSV_);
      float lp  = sh * __logf(ra) + (sh - 1.f) * __logf(dtp) - ra * dtp - lgamma_fast(sh);
      biasw[(size_t)(b * N_ + ibase + ii) * N_ + j] = (bias2[q][e] + gb20 + lp) * LOG2E_;
    }
  }
  grid_barrier(bar, 0);

  // ================= Phase 2: QKV projections (blocks 0..191) ==============
  if (bi < 192) {
    const int u = bi * 2 + (t >> 8);       // 384 units
    const int utid = t & 255;
    const int z  = u >> 7;                 // 0..2 (q,k,v)
    const int rem = u & 127;
    const int by = rem >> 5;               // 0..3
    const int bx = rem & 31;               // 0..31
    const int w = utid >> 6, l = utid & 63;
    const int r0 = bx * 64 + w * 16;
    const int c0 = by * 64;
    f32x4 acc[4];
    mfma_wave_pure(shi, slo, whi + z * 65536, wlo + z * 65536, r0, c0, l, acc);

    const int lr = l & 15, lg = l >> 4;
    if (z < 2) {
      unsigned short* dst = (z == 0) ? qbf : kbf;
#pragma unroll
      for (int ct = 0; ct < 4; ++ct) {
        int o = c0 + ct * 16 + lr, h = o >> 5, d = o & 31;
#pragma unroll
        for (int r = 0; r < 4; ++r) {
          int R = r0 + lg * 4 + r, b = R >> 10, n = R & 1023;
          dst[(size_t)((b * H_ + h) * N_ + n) * DH_ + d] = f2bf(acc[ct][r]);
        }
      }
    } else {
#pragma unroll
      for (int ct = 0; ct < 4; ++ct) {
        int o = c0 + ct * 16 + lr, h = o >> 5, d = o & 31;
#pragma unroll
        for (int r = 0; r < 4; ++r) {
          int R = r0 + lg * 4 + r, b = R >> 10, n = R & 1023;
          vtbf[(size_t)((b * H_ + h) * DH_ + d) * N_ + n] = f2bf(acc[ct][r]);
        }
      }
    }
  }
  grid_barrier(bar, 1);

  // ================= Phase 3: flash attention (all blocks) =================
  {
    const int w = t >> 6, l = t & 63;
    const int s = w >> 2, jq = w & 3;
    const int lr = l & 15, lg = l >> 4;
    const int bh = bi >> 5;
    const int qb = bi & 31;
    const int b = bh >> 3, h = bh & 7;
    const int ibase = qb * 32 + s * 16;

    const short8 ones8 = {16256, 16256, 16256, 16256, 16256, 16256, 16256, 16256};
    const short8 qfrag =
        *(const short8*)(qbf + (size_t)(bh * N_ + ibase + lr) * DH_ + lg * 8);
    const unsigned short* kb = kbf + (size_t)bh * N_ * DH_;
    const unsigned short* vb = vtbf + (size_t)bh * DH_ * N_;
    const float* bbase = biasw + (size_t)b * N_ * N_;

    f32x4 acc[2], accL;
    acc[0] = (f32x4){0.f, 0.f, 0.f, 0.f};
    acc[1] = (f32x4){0.f, 0.f, 0.f, 0.f};
    accL   = (f32x4){0.f, 0.f, 0.f, 0.f};
    float m_run[4];
#pragma unroll
    for (int r = 0; r < 4; ++r) m_run[r] = -3e38f;

    const int jbeg = jq * 256;
    for (int j0 = jbeg; j0 < jbeg + 256; j0 += 64) {
      f32x4 sc[4];
#pragma unroll
      for (int tt = 0; tt < 4; ++tt) {
        short8 kf = *(const short8*)(kb + (size_t)(j0 + tt * 16 + lr) * DH_ + lg * 8);
        sc[tt] = __builtin_amdgcn_mfma_f32_16x16x32_bf16(
            qfrag, kf, (f32x4){0.f, 0.f, 0.f, 0.f}, 0, 0, 0);
      }
#pragma unroll
      for (int r = 0; r < 4; ++r) {
        const float* bp = bbase + (size_t)(ibase + lg * 4 + r) * N_ + j0 + lr;
#pragma unroll
        for (int tt = 0; tt < 4; ++tt)
          sc[tt][r] = fmaf(sc[tt][r], SCALE2_, bp[tt * 16]);
      }
      float mt[4];
#pragma unroll
      for (int r = 0; r < 4; ++r)
        mt[r] = fmaxf(fmaxf(sc[0][r], sc[1][r]), fmaxf(sc[2][r], sc[3][r]));
#pragma unroll
      for (int off = 1; off < 16; off <<= 1)
#pragma unroll
        for (int r = 0; r < 4; ++r)
          mt[r] = fmaxf(mt[r], __shfl_xor(mt[r], off));
      float corr[4];
#pragma unroll
      for (int r = 0; r < 4; ++r) {
        float mn = fmaxf(m_run[r], mt[r]);
        corr[r] = exp2f(m_run[r] - mn);
        m_run[r] = mn;
      }
#pragma unroll
      for (int tt = 0; tt < 4; ++tt)
#pragma unroll
        for (int r = 0; r < 4; ++r)
          sc[tt][r] = exp2f(sc[tt][r] - m_run[r]);
#pragma unroll
      for (int r = 0; r < 4; ++r) {
        acc[0][r] *= corr[r];
        acc[1][r] *= corr[r];
        accL[r]   *= corr[r];
      }
#pragma unroll
      for (int tt = 0; tt < 4; ++tt)
#pragma unroll
        for (int r = 0; r < 4; ++r)
          p_lds[w][lg * 4 + r][tt * 16 + lr] = f2bf(sc[tt][r]);
#pragma unroll
      for (int kc = 0; kc < 2; ++kc) {
        short8 pf = *(const short8*)&p_lds[w][lr][kc * 32 + lg * 8];
#pragma unroll
        for (int c = 0; c < 2; ++c) {
          short8 vf = *(const short8*)(vb + (size_t)(c * 16 + lr) * N_ +
                                       j0 + kc * 32 + lg * 8);
          acc[c] = __builtin_amdgcn_mfma_f32_16x16x32_bf16(pf, vf, acc[c], 0, 0, 0);
        }
        accL = __builtin_amdgcn_mfma_f32_16x16x32_bf16(pf, ones8, accL, 0, 0, 0);
      }
    }

    if (jq > 0) {
#pragma unroll
      for (int c = 0; c < 2; ++c)
#pragma unroll
        for (int r = 0; r < 4; ++r)
          acc_lds[jq - 1][s][lg * 4 + r][c * 16 + lr] = acc[c][r];
      if (lr == 0) {
#pragma unroll
        for (int r = 0; r < 4; ++r) {
          ml_lds[jq - 1][s][lg * 4 + r][0] = m_run[r];
          ml_lds[jq - 1][s][lg * 4 + r][1] = accL[r];
        }
      }
    }
    __syncthreads();
    if (jq == 0) {
      float c0[4], cq[3][4], linv[4];
#pragma unroll
      for (int r = 0; r < 4; ++r) {
        int row = lg * 4 + r;
        float m = m_run[r];
#pragma unroll
        for (int q = 0; q < 3; ++q) m = fmaxf(m, ml_lds[q][s][row][0]);
        c0[r] = exp2f(m_run[r] - m);
        float lsum = accL[r] * c0[r];
#pragma unroll
        for (int q = 0; q < 3; ++q) {
          cq[q][r] = exp2f(ml_lds[q][s][row][0] - m);
          lsum = fmaf(ml_lds[q][s][row][1], cq[q][r], lsum);
        }
        linv[r] = 1.f / lsum;
      }
#pragma unroll
      for (int c = 0; c < 2; ++c) {
#pragma unroll
        for (int r = 0; r < 4; ++r) {
          int row = lg * 4 + r;
          int i = ibase + row;
          int d = c * 16 + lr;
          float o = acc[c][r] * c0[r];
#pragma unroll
          for (int q = 0; q < 3; ++q)
            o = fmaf(acc_lds[q][s][row][d], cq[q][r], o);
          o *= linv[r];
          size_t oidx = (size_t)(b * N_ + i) * D_ + h * DH_ + d;
          unsigned short hi = f2bf(o);
          ophi[oidx] = hi;
          oplo[oidx] = f2bf(o - bf2f(hi));
        }
      }
    }
  }
  grid_barrier(bar, 2);

  // ================= Phase 4: output projection (blocks 0..63) =============
  if (bi < 64) {
    const int u = bi * 2 + (t >> 8);       // 128 units
    const int utid = t & 255;
    const int by = u >> 5, bx = u & 31;
    const int w = utid >> 6, l = utid & 63;
    const int r0 = bx * 64 + w * 16;
    const int c0 = by * 64;
    f32x4 acc[4];
    mfma_wave_pure(ophi, oplo, whi + 3 * 65536, wlo + 3 * 65536, r0, c0, l, acc);
    const int lr = l & 15, lg = l >> 4;
#pragma unroll
    for (int ct = 0; ct < 4; ++ct)
#pragma unroll
      for (int r = 0; r < 4; ++r)
        out[(size_t)(r0 + lg * 4 + r) * D_ + c0 + ct * 16 + lr] = acc[ct][r];
  }
}

// ---------------------------------------------------------------------------
extern "C" void kernel_launch(void* const* d_in, const int* in_sizes, int n_in,
                              void* d_out, int out_size, void* d_ws, size_t ws_size,
                              hipStream_t stream) {
  const float* src    = (const float*)d_in[0];
  const float* coords = (const float*)d_in[1];
  const float* Wq  = (const float*)d_in[2];
  const float* Wk  = (const float*)d_in[3];
  const float* Wv  = (const float*)d_in[4];
  const float* Wo  = (const float*)d_in[5];
  const float* gw1 = (const float*)d_in[6];
  const float* gb1 = (const float*)d_in[7];
  const float* gw2 = (const float*)d_in[8];
  const float* gb2 = (const float*)d_in[9];
  const float* dw1 = (const float*)d_in[10];
  const float* db1 = (const float*)d_in[11];
  const float* dw2 = (const float*)d_in[12];
  const float* db2 = (const float*)d_in[13];
  float* out = (float*)d_out;

  char* wsb = (char*)d_ws;
  unsigned short* qbf  = (unsigned short*)wsb;                        // 1 MB
  unsigned short* kbf  = (unsigned short*)(wsb + (1 << 20));          // 1 MB
  unsigned short* vtbf = (unsigned short*)(wsb + (2 << 20));          // 1 MB
  float* biasw         = (float*)(wsb + (3 << 20));                   // 8 MB
  unsigned short* whi  = (unsigned short*)(wsb + (11 << 20));         // 512 KB
  unsigned short* wlo  = (unsigned short*)(wsb + (11 << 20) + (512 << 10));
  unsigned short* shi  = (unsigned short*)(wsb + (12 << 20));         // 1 MB
  unsigned short* slo  = (unsigned short*)(wsb + (13 << 20));         // 1 MB
  unsigned short* ophi = (unsigned short*)(wsb + (14 << 20));         // 1 MB
  unsigned short* oplo = (unsigned short*)(wsb + (15 << 20));         // 1 MB
  unsigned* bar        = (unsigned*)(wsb + (16 << 20));               // 64 B

  hipMemsetAsync(bar, 0, 64, stream);
  fused_kernel<<<GRID_, 512, 0, stream>>>(src, coords, Wq, Wk, Wv, Wo,
                                          gw1, gb1, gw2, gb2,
                                          dw1, db1, dw2, db2, out,
                                          qbf, kbf, vtbf, biasw,
                                          whi, wlo, shi, slo, ophi, oplo, bar);
}

// Round 10
// 92.906 us; speedup vs baseline: 2.5855x; 2.5855x over previous
//
#include <hip/hip_runtime.h>
#include <hip/hip_bf16.h>
#include <math.h>

constexpr int B_ = 2;
constexpr int N_ = 1024;
constexpr int D_ = 256;
constexpr int H_ = 8;
constexpr int DH_ = 32;
constexpr float SCALE_ = 0.17677669529663687f;  // 1/sqrt(32)
constexpr float LOG2E_ = 1.4426950408889634f;
constexpr float SCALE2_ = SCALE_ * LOG2E_;      // qk scale in exp2 domain
constexpr float EPSV_ = 1e-4f;

typedef __attribute__((ext_vector_type(8))) short short8;
typedef __attribute__((ext_vector_type(4))) float f32x4;
typedef __attribute__((ext_vector_type(2))) float f32x2;

__device__ __forceinline__ unsigned short f2bf(float x) {
  __hip_bfloat16 h = __float2bfloat16(x);
  return __builtin_bit_cast(unsigned short, h);
}
__device__ __forceinline__ float bf2f(unsigned short u) {
  unsigned int x = ((unsigned int)u) << 16;
  return __builtin_bit_cast(float, x);
}
__device__ __forceinline__ f32x2 max2(f32x2 a, f32x2 b) {
  return __builtin_elementwise_max(a, b);
}

__device__ __forceinline__ float lgamma_fast(float x) {
  float y = (x < 1.f) ? x : (x - 1.f);
  float g = fmaf(y, 0.035868343f, -0.193527818f);
  g = fmaf(y, g, 0.482199394f);
  g = fmaf(y, g, -0.756704078f);
  g = fmaf(y, g, 0.918206857f);
  g = fmaf(y, g, -0.897056937f);
  g = fmaf(y, g, 0.988205891f);
  g = fmaf(y, g, -0.577191652f);
  g = fmaf(y, g, 1.0f);
  float lg = __logf(g);
  return (x < 1.f) ? lg - __logf(x) : lg;
}
__device__ __forceinline__ float softplus_fast(float x) {
  return __logf(1.f + __expf(x));
}

// ---------------------------------------------------------------------------
// Pure-load split-bf16 MFMA GEMM wave body. C[16 rows][64 cols] per wave.
// acc row = (l>>4)*4 + reg, col = ct*16 + (l&15)  [m89/m91 layout].
// ---------------------------------------------------------------------------
__device__ __forceinline__
void mfma_wave_pure(const unsigned short* __restrict__ Ahi,
                    const unsigned short* __restrict__ Alo,
                    const unsigned short* __restrict__ whi,
                    const unsigned short* __restrict__ wlo,
                    int r0, int c0, f32x4 (&acc)[4]) {
  const int l = threadIdx.x & 63;
  const int lr = l & 15, lg = l >> 4;
#pragma unroll
  for (int ct = 0; ct < 4; ++ct) acc[ct] = (f32x4){0.f, 0.f, 0.f, 0.f};
#pragma unroll 2
  for (int ks = 0; ks < 8; ++ks) {
    size_t aoff = (size_t)(r0 + lr) * D_ + ks * 32 + lg * 8;
    short8 ahi = *(const short8*)(Ahi + aoff);
    short8 alo = *(const short8*)(Alo + aoff);
#pragma unroll
    for (int ct = 0; ct < 4; ++ct) {
      size_t woff = (size_t)(c0 + ct * 16 + lr) * D_ + ks * 32 + lg * 8;
      short8 wh = *(const short8*)(whi + woff);
      short8 wl = *(const short8*)(wlo + woff);
      acc[ct] = __builtin_amdgcn_mfma_f32_16x16x32_bf16(ahi, wh, acc[ct], 0, 0, 0);
      acc[ct] = __builtin_amdgcn_mfma_f32_16x16x32_bf16(alo, wh, acc[ct], 0, 0, 0);
      acc[ct] = __builtin_amdgcn_mfma_f32_16x16x32_bf16(ahi, wl, acc[ct], 0, 0, 0);
    }
  }
}

// ---------------------------------------------------------------------------
// QKV projections. grid (32, 4, 3); 4 waves/block.
// ---------------------------------------------------------------------------
__global__ __launch_bounds__(256)
void qkv_kernel(const unsigned short* __restrict__ shi,
                const unsigned short* __restrict__ slo,
                const unsigned short* __restrict__ whi,
                const unsigned short* __restrict__ wlo,
                unsigned short* __restrict__ qbf, unsigned short* __restrict__ kbf,
                unsigned short* __restrict__ vtbf) {
  const int z = blockIdx.z;
  const int w = threadIdx.x >> 6;
  const int r0 = blockIdx.x * 64 + w * 16;
  const int c0 = blockIdx.y * 64;
  f32x4 acc[4];
  mfma_wave_pure(shi, slo, whi + z * 65536, wlo + z * 65536, r0, c0, acc);

  const int l = threadIdx.x & 63, lr = l & 15, lg = l >> 4;
  if (z < 2) {
    unsigned short* dst = (z == 0) ? qbf : kbf;
#pragma unroll
    for (int ct = 0; ct < 4; ++ct) {
      int o = c0 + ct * 16 + lr, h = o >> 5, d = o & 31;
#pragma unroll
      for (int r = 0; r < 4; ++r) {
        int R = r0 + lg * 4 + r, b = R >> 10, n = R & 1023;
        dst[(size_t)((b * H_ + h) * N_ + n) * DH_ + d] = f2bf(acc[ct][r]);
      }
    }
  } else {
#pragma unroll
    for (int ct = 0; ct < 4; ++ct) {
      int o = c0 + ct * 16 + lr, h = o >> 5, d = o & 31;
#pragma unroll
      for (int r = 0; r < 4; ++r) {
        int R = r0 + lg * 4 + r, b = R >> 10, n = R & 1023;
        vtbf[(size_t)((b * H_ + h) * DH_ + d) * N_ + n] = f2bf(acc[ct][r]);
      }
    }
  }
}

// ---------------------------------------------------------------------------
// Output projection: A = attn output pre-split (hi/lo bf16), f32 out.
// ---------------------------------------------------------------------------
__global__ __launch_bounds__(256)
void projo_kernel(const unsigned short* __restrict__ ophi,
                  const unsigned short* __restrict__ oplo,
                  const unsigned short* __restrict__ whi,
                  const unsigned short* __restrict__ wlo,
                  float* __restrict__ out) {
  const int w = threadIdx.x >> 6;
  const int r0 = blockIdx.x * 64 + w * 16;
  const int c0 = blockIdx.y * 64;
  f32x4 acc[4];
  mfma_wave_pure(ophi, oplo, whi + 3 * 65536, wlo + 3 * 65536, r0, c0, acc);
  const int l = threadIdx.x & 63, lr = l & 15, lg = l >> 4;
#pragma unroll
  for (int ct = 0; ct < 4; ++ct)
#pragma unroll
    for (int r = 0; r < 4; ++r)
      out[(size_t)(r0 + lg * 4 + r) * D_ + c0 + ct * 16 + lr] = acc[ct][r];
}

// ---------------------------------------------------------------------------
// Fused pair-bias + one-shot hi/lo split kernel, v5.
// Bias blocks 0..511: one j/thread, SIXTEEN i's/thread, weights via 3 LDS
// float4 broadcasts per h (amortized over 16 pairs), ci staged in LDS.
// v3 had this structure but spilled at VGPR=64 (plain launch_bounds let the
// compiler chase 8 waves/SIMD); __launch_bounds__(256,4) sets the budget to
// 128 VGPR -- the ~115-reg live set fits, no scratch.  v4's per-h global
// weight reads (704 loads/wave, 8-pair amortization) were the 38us cost.
// Blocks 512..703: split W (256K f32) + src (512K f32) into bf16 hi/lo.
// ---------------------------------------------------------------------------
__global__ __launch_bounds__(256, 4)
void bias_split_kernel(const float* __restrict__ coords,
                 const float* __restrict__ gw1, const float* __restrict__ gb1,
                 const float* __restrict__ gw2, const float* __restrict__ gb2,
                 const float* __restrict__ dw1, const float* __restrict__ db1,
                 const float* __restrict__ dw2, const float* __restrict__ db2,
                 float* __restrict__ bias,
                 const float* __restrict__ Wq, const float* __restrict__ Wk,
                 const float* __restrict__ Wv, const float* __restrict__ Wo,
                 const float* __restrict__ src,
                 unsigned short* __restrict__ whi, unsigned short* __restrict__ wlo,
                 unsigned short* __restrict__ shi, unsigned short* __restrict__ slo) {
  const int tid = threadIdx.x;
  const int bi = blockIdx.x;

  if (bi >= 512) {  // ---- split region ----
    int t = (bi - 512) * 256 + tid;   // 0..49151, 16 floats each
    int idx = t * 16;
    const float* p;
    unsigned short *dhi, *dlo;
    if (idx < 262144) {               // W tables
      int m = idx >> 16;
      int off = idx & 65535;
      p = (m == 0) ? Wq : (m == 1) ? Wk : (m == 2) ? Wv : Wo;
      p += off;
      dhi = whi + idx; dlo = wlo + idx;
    } else {                          // src
      int off = idx - 262144;
      p = src + off;
      dhi = shi + off; dlo = slo + off;
    }
#pragma unroll
    for (int q = 0; q < 4; ++q) {
      float4 f = *(const float4*)(p + q * 4);
      ushort4 hi, lo;
      hi.x = f2bf(f.x); lo.x = f2bf(f.x - bf2f(hi.x));
      hi.y = f2bf(f.y); lo.y = f2bf(f.y - bf2f(hi.y));
      hi.z = f2bf(f.z); lo.z = f2bf(f.z - bf2f(hi.z));
      hi.w = f2bf(f.w); lo.w = f2bf(f.w - bf2f(hi.w));
      *(ushort4*)(dhi + q * 4) = hi;
      *(ushort4*)(dlo + q * 4) = lo;
    }
    return;
  }

  // ---- bias region: bi = b*256 + it*4 + jt ----
  __shared__ float4 swA[64];   // g0, g1, gb1, g2
  __shared__ float4 swB[64];   // d_dist, d_x, d_y, d_z
  __shared__ float4 swC[64];   // db1, w0, w1, pad
  __shared__ float4 ci_lds[16];

  const int rem = bi & 255;
  const int jt = rem & 3;           // 4 j-tiles of 256
  const int it = rem >> 2;          // 64 i-tiles of 16
  const int b  = bi >> 8;
  const int j  = jt * 256 + tid;
  const int ibase = it * 16;

  if (tid < 64) {
    int h = tid;
    swA[h] = make_float4(gw1[2 * h], gw1[2 * h + 1], gb1[h], gw2[h]);
    swB[h] = make_float4(dw1[4 * h], dw1[4 * h + 1], dw1[4 * h + 2], dw1[4 * h + 3]);
    swC[h] = make_float4(db1[h], dw2[h], dw2[64 + h], 0.f);
  } else if (tid < 80) {
    ci_lds[tid - 64] = ((const float4*)coords)[b * N_ + ibase + (tid - 64)];
  }
  __syncthreads();

  const float4 cj = ((const float4*)coords)[b * N_ + j];
  f32x2 dist2[8], dtv2[8];
#pragma unroll
  for (int q = 0; q < 8; ++q) {
#pragma unroll
    for (int e = 0; e < 2; ++e) {
      float4 ci = ci_lds[q * 2 + e];
      float dx = ci.x - cj.x, dy = ci.y - cj.y, dz = ci.z - cj.z;
      dist2[q][e] = sqrtf(dx * dx + dy * dy + dz * dz);
      dtv2[q][e]  = ci.w - cj.w;
    }
  }

  const float db20 = db2[0], db21 = db2[1], gb20 = gb2[0];
  f32x2 bias2[8], r02[8], r12[8];
#pragma unroll
  for (int q = 0; q < 8; ++q) {
    bias2[q] = (f32x2){0.f, 0.f};
    r02[q]   = (f32x2){db20, db20};
    r12[q]   = (f32x2){db21, db21};
  }

#pragma unroll 2
  for (int h = 0; h < 64; ++h) {
    float4 a = swA[h], w = swB[h], c = swC[h];   // 3 broadcast ds_read_b128
    float dp = fmaf(w.y, cj.x, fmaf(w.z, cj.y, fmaf(w.w, cj.z, c.x)));
    f32x2 g0v = {a.x, a.x}, g1v = {a.y, a.y}, gbv = {a.z, a.z}, g2v = {a.w, a.w};
    f32x2 w0v = {w.x, w.x}, dpv = {dp, dp}, c1v = {c.y, c.y}, c2v = {c.z, c.z};
    const f32x2 zero = {0.f, 0.f};
#pragma unroll
    for (int q = 0; q < 8; ++q) {
      f32x2 g = g0v * dist2[q] + g1v * dtv2[q] + gbv;
      bias2[q] += g2v * max2(g, zero);
      f32x2 dhv = max2(w0v * dist2[q] + dpv, zero);
      r02[q] += c1v * dhv;
      r12[q] += c2v * dhv;
    }
  }

#pragma unroll 4
  for (int ii = 0; ii < 16; ++ii) {
    int q = ii >> 1, e = ii & 1;
    float sh  = softplus_fast(r02[q][e]) + EPSV_;
    float ra  = softplus_fast(r12[q][e]) + EPSV_;
    float dtp = fmaxf(fabsf(dtv2[q][e]), EPSV_);
    float lp  = sh * __logf(ra) + (sh - 1.f) * __logf(dtp) - ra * dtp - lgamma_fast(sh);
    bias[(size_t)(b * N_ + ibase + ii) * N_ + j] = (bias2[q][e] + gb20 + lp) * LOG2E_;
  }
}

// ---------------------------------------------------------------------------
// MFMA flash attention, 4-way split-j, exp2 domain (round-8 version).
// ---------------------------------------------------------------------------
__global__ __launch_bounds__(512)
void attn_kernel(const unsigned short* __restrict__ qbf,
                 const unsigned short* __restrict__ kbf,
                 const unsigned short* __restrict__ vtbf,
                 const float* __restrict__ biasg,
                 unsigned short* __restrict__ ophi,
                 unsigned short* __restrict__ oplo) {
  __shared__ __align__(16) unsigned short p_lds[8][16][72];
  __shared__ float acc_lds[3][2][16][32];
  __shared__ float ml_lds[3][2][16][2];

  const int tid = threadIdx.x;
  const int w = tid >> 6, l = tid & 63;
  const int s = w >> 2, jq = w & 3;
  const int lr = l & 15, lg = l >> 4;
  const int bh = blockIdx.x >> 5;
  const int qb = blockIdx.x & 31;
  const int b = bh >> 3, h = bh & 7;
  const int ibase = qb * 32 + s * 16;

  const short8 ones8 = {16256, 16256, 16256, 16256, 16256, 16256, 16256, 16256};

  const short8 qfrag =
      *(const short8*)(qbf + (size_t)(bh * N_ + ibase + lr) * DH_ + lg * 8);
  const unsigned short* kb = kbf + (size_t)bh * N_ * DH_;
  const unsigned short* vb = vtbf + (size_t)bh * DH_ * N_;
  const float* bbase = biasg + (size_t)b * N_ * N_;

  f32x4 acc[2], accL;
  acc[0] = (f32x4){0.f, 0.f, 0.f, 0.f};
  acc[1] = (f32x4){0.f, 0.f, 0.f, 0.f};
  accL   = (f32x4){0.f, 0.f, 0.f, 0.f};
  float m_run[4];
#pragma unroll
  for (int r = 0; r < 4; ++r) m_run[r] = -3e38f;

  const int jbeg = jq * 256;
  for (int j0 = jbeg; j0 < jbeg + 256; j0 += 64) {
    f32x4 sc[4];
#pragma unroll
    for (int t = 0; t < 4; ++t) {
      short8 kf = *(const short8*)(kb + (size_t)(j0 + t * 16 + lr) * DH_ + lg * 8);
      sc[t] = __builtin_amdgcn_mfma_f32_16x16x32_bf16(
          qfrag, kf, (f32x4){0.f, 0.f, 0.f, 0.f}, 0, 0, 0);
    }
#pragma unroll
    for (int r = 0; r < 4; ++r) {
      const float* bi = bbase + (size_t)(ibase + lg * 4 + r) * N_ + j0 + lr;
#pragma unroll
      for (int t = 0; t < 4; ++t)
        sc[t][r] = fmaf(sc[t][r], SCALE2_, bi[t * 16]);
    }
    float mt[4];
#pragma unroll
    for (int r = 0; r < 4; ++r)
      mt[r] = fmaxf(fmaxf(sc[0][r], sc[1][r]), fmaxf(sc[2][r], sc[3][r]));
#pragma unroll
    for (int off = 1; off < 16; off <<= 1)
#pragma unroll
      for (int r = 0; r < 4; ++r)
        mt[r] = fmaxf(mt[r], __shfl_xor(mt[r], off));
    float corr[4];
#pragma unroll
    for (int r = 0; r < 4; ++r) {
      float mn = fmaxf(m_run[r], mt[r]);
      corr[r] = exp2f(m_run[r] - mn);
      m_run[r] = mn;
    }
#pragma unroll
    for (int t = 0; t < 4; ++t)
#pragma unroll
      for (int r = 0; r < 4; ++r)
        sc[t][r] = exp2f(sc[t][r] - m_run[r]);
#pragma unroll
    for (int r = 0; r < 4; ++r) {
      acc[0][r] *= corr[r];
      acc[1][r] *= corr[r];
      accL[r]   *= corr[r];
    }
#pragma unroll
    for (int t = 0; t < 4; ++t)
#pragma unroll
      for (int r = 0; r < 4; ++r)
        p_lds[w][lg * 4 + r][t * 16 + lr] = f2bf(sc[t][r]);
#pragma unroll
    for (int kc = 0; kc < 2; ++kc) {
      short8 pf = *(const short8*)&p_lds[w][lr][kc * 32 + lg * 8];
#pragma unroll
      for (int c = 0; c < 2; ++c) {
        short8 vf = *(const short8*)(vb + (size_t)(c * 16 + lr) * N_ +
                                     j0 + kc * 32 + lg * 8);
        acc[c] = __builtin_amdgcn_mfma_f32_16x16x32_bf16(pf, vf, acc[c], 0, 0, 0);
      }
      accL = __builtin_amdgcn_mfma_f32_16x16x32_bf16(pf, ones8, accL, 0, 0, 0);
    }
  }

  if (jq > 0) {
#pragma unroll
    for (int c = 0; c < 2; ++c)
#pragma unroll
      for (int r = 0; r < 4; ++r)
        acc_lds[jq - 1][s][lg * 4 + r][c * 16 + lr] = acc[c][r];
    if (lr == 0) {
#pragma unroll
      for (int r = 0; r < 4; ++r) {
        ml_lds[jq - 1][s][lg * 4 + r][0] = m_run[r];
        ml_lds[jq - 1][s][lg * 4 + r][1] = accL[r];
      }
    }
  }
  __syncthreads();
  if (jq == 0) {
    float c0[4], cq[3][4], linv[4];
#pragma unroll
    for (int r = 0; r < 4; ++r) {
      int row = lg * 4 + r;
      float m = m_run[r];
#pragma unroll
      for (int q = 0; q < 3; ++q) m = fmaxf(m, ml_lds[q][s][row][0]);
      c0[r] = exp2f(m_run[r] - m);
      float lsum = accL[r] * c0[r];
#pragma unroll
      for (int q = 0; q < 3; ++q) {
        cq[q][r] = exp2f(ml_lds[q][s][row][0] - m);
        lsum = fmaf(ml_lds[q][s][row][1], cq[q][r], lsum);
      }
      linv[r] = 1.f / lsum;
    }
#pragma unroll
    for (int c = 0; c < 2; ++c) {
#pragma unroll
      for (int r = 0; r < 4; ++r) {
        int row = lg * 4 + r;
        int i = ibase + row;
        int d = c * 16 + lr;
        float o = acc[c][r] * c0[r];
#pragma unroll
        for (int q = 0; q < 3; ++q)
          o = fmaf(acc_lds[q][s][row][d], cq[q][r], o);
        o *= linv[r];
        size_t oidx = (size_t)(b * N_ + i) * D_ + h * DH_ + d;
        unsigned short hi = f2bf(o);
        ophi[oidx] = hi;
        oplo[oidx] = f2bf(o - bf2f(hi));
      }
    }
  }
}

// ---------------------------------------------------------------------------
extern "C" void kernel_launch(void* const* d_in, const int* in_sizes, int n_in,
                              void* d_out, int out_size, void* d_ws, size_t ws_size,
                              hipStream_t stream) {
  const float* src    = (const float*)d_in[0];
  const float* coords = (const float*)d_in[1];
  const float* Wq  = (const float*)d_in[2];
  const float* Wk  = (const float*)d_in[3];
  const float* Wv  = (const float*)d_in[4];
  const float* Wo  = (const float*)d_in[5];
  const float* gw1 = (const float*)d_in[6];
  const float* gb1 = (const float*)d_in[7];
  const float* gw2 = (const float*)d_in[8];
  const float* gb2 = (const float*)d_in[9];
  const float* dw1 = (const float*)d_in[10];
  const float* db1 = (const float*)d_in[11];
  const float* dw2 = (const float*)d_in[12];
  const float* db2 = (const float*)d_in[13];
  float* out = (float*)d_out;

  char* wsb = (char*)d_ws;
  unsigned short* qbf  = (unsigned short*)wsb;                        // 1 MB
  unsigned short* kbf  = (unsigned short*)(wsb + (1 << 20));          // 1 MB
  unsigned short* vtbf = (unsigned short*)(wsb + (2 << 20));          // 1 MB
  float* biasw         = (float*)(wsb + (3 << 20));                   // 8 MB
  unsigned short* whi  = (unsigned short*)(wsb + (11 << 20));         // 512 KB
  unsigned short* wlo  = (unsigned short*)(wsb + (11 << 20) + (512 << 10));
  unsigned short* shi  = (unsigned short*)(wsb + (12 << 20));         // 1 MB
  unsigned short* slo  = (unsigned short*)(wsb + (13 << 20));         // 1 MB
  unsigned short* ophi = (unsigned short*)(wsb + (14 << 20));         // 1 MB
  unsigned short* oplo = (unsigned short*)(wsb + (15 << 20));         // 1 MB

  bias_split_kernel<<<704, 256, 0, stream>>>(coords, gw1, gb1, gw2, gb2,
                                             dw1, db1, dw2, db2, biasw,
                                             Wq, Wk, Wv, Wo, src,
                                             whi, wlo, shi, slo);
  qkv_kernel<<<dim3(32, 4, 3), 256, 0, stream>>>(shi, slo, whi, wlo, qbf, kbf, vtbf);
  attn_kernel<<<512, 512, 0, stream>>>(qbf, kbf, vtbf, biasw, ophi, oplo);
  projo_kernel<<<dim3(32, 4), 256, 0, stream>>>(ophi, oplo, whi, wlo, out);
}

// Round 11
// 89.926 us; speedup vs baseline: 2.6712x; 1.0331x over previous
//
#include <hip/hip_runtime.h>
#include <hip/hip_bf16.h>
#include <math.h>

constexpr int B_ = 2;
constexpr int N_ = 1024;
constexpr int D_ = 256;
constexpr int H_ = 8;
constexpr int DH_ = 32;
constexpr float SCALE_ = 0.17677669529663687f;  // 1/sqrt(32)
constexpr float LOG2E_ = 1.4426950408889634f;
constexpr float SCALE2_ = SCALE_ * LOG2E_;      // qk scale in exp2 domain
constexpr float EPSV_ = 1e-4f;

typedef __attribute__((ext_vector_type(8))) short short8;
typedef __attribute__((ext_vector_type(4))) float f32x4;

__device__ __forceinline__ unsigned short f2bf(float x) {
  __hip_bfloat16 h = __float2bfloat16(x);
  return __builtin_bit_cast(unsigned short, h);
}
__device__ __forceinline__ float bf2f(unsigned short u) {
  unsigned int x = ((unsigned int)u) << 16;
  return __builtin_bit_cast(float, x);
}

__device__ __forceinline__ float lgamma_fast(float x) {
  float y = (x < 1.f) ? x : (x - 1.f);
  float g = fmaf(y, 0.035868343f, -0.193527818f);
  g = fmaf(y, g, 0.482199394f);
  g = fmaf(y, g, -0.756704078f);
  g = fmaf(y, g, 0.918206857f);
  g = fmaf(y, g, -0.897056937f);
  g = fmaf(y, g, 0.988205891f);
  g = fmaf(y, g, -0.577191652f);
  g = fmaf(y, g, 1.0f);
  float lg = __logf(g);
  return (x < 1.f) ? lg - __logf(x) : lg;
}
__device__ __forceinline__ float softplus_fast(float x) {
  return __logf(1.f + __expf(x));
}

// ---------------------------------------------------------------------------
// Pure-load split-bf16 MFMA GEMM wave body. C[16 rows][64 cols] per wave.
// acc row = (l>>4)*4 + reg, col = ct*16 + (l&15)  [m89/m91 layout].
// ---------------------------------------------------------------------------
__device__ __forceinline__
void mfma_wave_pure(const unsigned short* __restrict__ Ahi,
                    const unsigned short* __restrict__ Alo,
                    const unsigned short* __restrict__ whi,
                    const unsigned short* __restrict__ wlo,
                    int r0, int c0, f32x4 (&acc)[4]) {
  const int l = threadIdx.x & 63;
  const int lr = l & 15, lg = l >> 4;
#pragma unroll
  for (int ct = 0; ct < 4; ++ct) acc[ct] = (f32x4){0.f, 0.f, 0.f, 0.f};
#pragma unroll 2
  for (int ks = 0; ks < 8; ++ks) {
    size_t aoff = (size_t)(r0 + lr) * D_ + ks * 32 + lg * 8;
    short8 ahi = *(const short8*)(Ahi + aoff);
    short8 alo = *(const short8*)(Alo + aoff);
#pragma unroll
    for (int ct = 0; ct < 4; ++ct) {
      size_t woff = (size_t)(c0 + ct * 16 + lr) * D_ + ks * 32 + lg * 8;
      short8 wh = *(const short8*)(whi + woff);
      short8 wl = *(const short8*)(wlo + woff);
      acc[ct] = __builtin_amdgcn_mfma_f32_16x16x32_bf16(ahi, wh, acc[ct], 0, 0, 0);
      acc[ct] = __builtin_amdgcn_mfma_f32_16x16x32_bf16(alo, wh, acc[ct], 0, 0, 0);
      acc[ct] = __builtin_amdgcn_mfma_f32_16x16x32_bf16(ahi, wl, acc[ct], 0, 0, 0);
    }
  }
}

// ---------------------------------------------------------------------------
// QKV projections. grid (32, 4, 3); 4 waves/block.
// ---------------------------------------------------------------------------
__global__ __launch_bounds__(256)
void qkv_kernel(const unsigned short* __restrict__ shi,
                const unsigned short* __restrict__ slo,
                const unsigned short* __restrict__ whi,
                const unsigned short* __restrict__ wlo,
                unsigned short* __restrict__ qbf, unsigned short* __restrict__ kbf,
                unsigned short* __restrict__ vtbf) {
  const int z = blockIdx.z;
  const int w = threadIdx.x >> 6;
  const int r0 = blockIdx.x * 64 + w * 16;
  const int c0 = blockIdx.y * 64;
  f32x4 acc[4];
  mfma_wave_pure(shi, slo, whi + z * 65536, wlo + z * 65536, r0, c0, acc);

  const int l = threadIdx.x & 63, lr = l & 15, lg = l >> 4;
  if (z < 2) {
    unsigned short* dst = (z == 0) ? qbf : kbf;
#pragma unroll
    for (int ct = 0; ct < 4; ++ct) {
      int o = c0 + ct * 16 + lr, h = o >> 5, d = o & 31;
#pragma unroll
      for (int r = 0; r < 4; ++r) {
        int R = r0 + lg * 4 + r, b = R >> 10, n = R & 1023;
        dst[(size_t)((b * H_ + h) * N_ + n) * DH_ + d] = f2bf(acc[ct][r]);
      }
    }
  } else {
#pragma unroll
    for (int ct = 0; ct < 4; ++ct) {
      int o = c0 + ct * 16 + lr, h = o >> 5, d = o & 31;
#pragma unroll
      for (int r = 0; r < 4; ++r) {
        int R = r0 + lg * 4 + r, b = R >> 10, n = R & 1023;
        vtbf[(size_t)((b * H_ + h) * DH_ + d) * N_ + n] = f2bf(acc[ct][r]);
      }
    }
  }
}

// ---------------------------------------------------------------------------
// Output projection: A = attn output pre-split (hi/lo bf16), f32 out.
// ---------------------------------------------------------------------------
__global__ __launch_bounds__(256)
void projo_kernel(const unsigned short* __restrict__ ophi,
                  const unsigned short* __restrict__ oplo,
                  const unsigned short* __restrict__ whi,
                  const unsigned short* __restrict__ wlo,
                  float* __restrict__ out) {
  const int w = threadIdx.x >> 6;
  const int r0 = blockIdx.x * 64 + w * 16;
  const int c0 = blockIdx.y * 64;
  f32x4 acc[4];
  mfma_wave_pure(ophi, oplo, whi + 3 * 65536, wlo + 3 * 65536, r0, c0, acc);
  const int l = threadIdx.x & 63, lr = l & 15, lg = l >> 4;
#pragma unroll
  for (int ct = 0; ct < 4; ++ct)
#pragma unroll
    for (int r = 0; r < 4; ++r)
      out[(size_t)(r0 + lg * 4 + r) * D_ + c0 + ct * 16 + lr] = acc[ct][r];
}

// ---------------------------------------------------------------------------
// Fused pair-bias + hi/lo split kernel, v6.
// Design rationale (from measured v2/v4/v5 all landing 38-45us):
//  - weights are WAVE-UNIFORM -> read via uniform global loads (s_load from
//    the scalar K$): zero VALU and zero LDS cost, separate issue pipe.
//  - 4 pairs/thread -> live set ~40 f32 -> VGPR<=64 WITHOUT spills (v5 spilled
//    ~8MB scratch; v4/v5 WRITE_SIZE 19.5MB vs 11MB real output).
//  - 2048 bias blocks = 8192 waves = 8 waves/SIMD: latency fully hidden
//    (v5 had 2 waves/SIMD, 43% idle). VALU-issue floor ~15us.
// Blocks 2048..2239: split W (256K f32) + src (512K f32) into bf16 hi/lo.
// ---------------------------------------------------------------------------
__global__ __launch_bounds__(256)
void bias_split_kernel(const float* __restrict__ coords,
                 const float* __restrict__ gw1, const float* __restrict__ gb1,
                 const float* __restrict__ gw2, const float* __restrict__ gb2,
                 const float* __restrict__ dw1, const float* __restrict__ db1,
                 const float* __restrict__ dw2, const float* __restrict__ db2,
                 float* __restrict__ bias,
                 const float* __restrict__ Wq, const float* __restrict__ Wk,
                 const float* __restrict__ Wv, const float* __restrict__ Wo,
                 const float* __restrict__ src,
                 unsigned short* __restrict__ whi, unsigned short* __restrict__ wlo,
                 unsigned short* __restrict__ shi, unsigned short* __restrict__ slo) {
  const int tid = threadIdx.x;
  const int bi = blockIdx.x;

  if (bi >= 2048) {  // ---- split region ----
    int t = (bi - 2048) * 256 + tid;   // 0..49151, 16 floats each
    int idx = t * 16;
    const float* p;
    unsigned short *dhi, *dlo;
    if (idx < 262144) {               // W tables
      int m = idx >> 16;
      int off = idx & 65535;
      p = (m == 0) ? Wq : (m == 1) ? Wk : (m == 2) ? Wv : Wo;
      p += off;
      dhi = whi + idx; dlo = wlo + idx;
    } else {                          // src
      int off = idx - 262144;
      p = src + off;
      dhi = shi + off; dlo = slo + off;
    }
#pragma unroll
    for (int q = 0; q < 4; ++q) {
      float4 f = *(const float4*)(p + q * 4);
      ushort4 hi, lo;
      hi.x = f2bf(f.x); lo.x = f2bf(f.x - bf2f(hi.x));
      hi.y = f2bf(f.y); lo.y = f2bf(f.y - bf2f(hi.y));
      hi.z = f2bf(f.z); lo.z = f2bf(f.z - bf2f(hi.z));
      hi.w = f2bf(f.w); lo.w = f2bf(f.w - bf2f(hi.w));
      *(ushort4*)(dhi + q * 4) = hi;
      *(ushort4*)(dlo + q * 4) = lo;
    }
    return;
  }

  // ---- bias region: bi = b*1024 + it*4 + jt ----
  const int jt = bi & 3;            // 4 j-tiles of 256
  const int it = (bi >> 2) & 255;   // 256 i-tiles of 4
  const int b  = bi >> 10;
  const int j  = jt * 256 + tid;
  const int ibase = it * 4;

  const float4 cj = ((const float4*)coords)[b * N_ + j];

  float dist[4], dtv[4];
#pragma unroll
  for (int ii = 0; ii < 4; ++ii) {
    // uniform address -> scalar (s_load) broadcast
    const float* cp = coords + 4 * (b * N_ + ibase + ii);
    float dx = cp[0] - cj.x, dy = cp[1] - cj.y, dz = cp[2] - cj.z;
    dist[ii] = sqrtf(dx * dx + dy * dy + dz * dz);
    dtv[ii]  = cp[3] - cj.w;
  }

  const float db20 = db2[0], db21 = db2[1], gb20 = gb2[0];
  float biasv[4], raw0[4], raw1[4];
#pragma unroll
  for (int ii = 0; ii < 4; ++ii) { biasv[ii] = 0.f; raw0[ii] = db20; raw1[ii] = db21; }

#pragma unroll 4
  for (int h = 0; h < 64; ++h) {
    // all wave-uniform -> s_load from scalar cache (separate issue pipe)
    float g0 = gw1[2 * h], g1 = gw1[2 * h + 1], gb = gb1[h], g2 = gw2[h];
    float w0 = dw1[4 * h], wx = dw1[4 * h + 1], wy = dw1[4 * h + 2], wz = dw1[4 * h + 3];
    float c0 = db1[h], c1 = dw2[h], c2 = dw2[64 + h];
    float dp = fmaf(wx, cj.x, fmaf(wy, cj.y, fmaf(wz, cj.z, c0)));
#pragma unroll
    for (int ii = 0; ii < 4; ++ii) {
      float g = fmaf(g0, dist[ii], fmaf(g1, dtv[ii], gb));
      biasv[ii] = fmaf(g2, fmaxf(g, 0.f), biasv[ii]);
      float dh_ = fmaxf(fmaf(w0, dist[ii], dp), 0.f);
      raw0[ii] = fmaf(c1, dh_, raw0[ii]);
      raw1[ii] = fmaf(c2, dh_, raw1[ii]);
    }
  }

#pragma unroll
  for (int ii = 0; ii < 4; ++ii) {
    float sh  = softplus_fast(raw0[ii]) + EPSV_;
    float ra  = softplus_fast(raw1[ii]) + EPSV_;
    float dtp = fmaxf(fabsf(dtv[ii]), EPSV_);
    float lp  = sh * __logf(ra) + (sh - 1.f) * __logf(dtp) - ra * dtp - lgamma_fast(sh);
    bias[(size_t)(b * N_ + ibase + ii) * N_ + j] = (biasv[ii] + gb20 + lp) * LOG2E_;
  }
}

// ---------------------------------------------------------------------------
// MFMA flash attention, 4-way split-j, exp2 domain (round-8 version).
// ---------------------------------------------------------------------------
__global__ __launch_bounds__(512)
void attn_kernel(const unsigned short* __restrict__ qbf,
                 const unsigned short* __restrict__ kbf,
                 const unsigned short* __restrict__ vtbf,
                 const float* __restrict__ biasg,
                 unsigned short* __restrict__ ophi,
                 unsigned short* __restrict__ oplo) {
  __shared__ __align__(16) unsigned short p_lds[8][16][72];
  __shared__ float acc_lds[3][2][16][32];
  __shared__ float ml_lds[3][2][16][2];

  const int tid = threadIdx.x;
  const int w = tid >> 6, l = tid & 63;
  const int s = w >> 2, jq = w & 3;
  const int lr = l & 15, lg = l >> 4;
  const int bh = blockIdx.x >> 5;
  const int qb = blockIdx.x & 31;
  const int b = bh >> 3, h = bh & 7;
  const int ibase = qb * 32 + s * 16;

  const short8 ones8 = {16256, 16256, 16256, 16256, 16256, 16256, 16256, 16256};

  const short8 qfrag =
      *(const short8*)(qbf + (size_t)(bh * N_ + ibase + lr) * DH_ + lg * 8);
  const unsigned short* kb = kbf + (size_t)bh * N_ * DH_;
  const unsigned short* vb = vtbf + (size_t)bh * DH_ * N_;
  const float* bbase = biasg + (size_t)b * N_ * N_;

  f32x4 acc[2], accL;
  acc[0] = (f32x4){0.f, 0.f, 0.f, 0.f};
  acc[1] = (f32x4){0.f, 0.f, 0.f, 0.f};
  accL   = (f32x4){0.f, 0.f, 0.f, 0.f};
  float m_run[4];
#pragma unroll
  for (int r = 0; r < 4; ++r) m_run[r] = -3e38f;

  const int jbeg = jq * 256;
  for (int j0 = jbeg; j0 < jbeg + 256; j0 += 64) {
    f32x4 sc[4];
#pragma unroll
    for (int t = 0; t < 4; ++t) {
      short8 kf = *(const short8*)(kb + (size_t)(j0 + t * 16 + lr) * DH_ + lg * 8);
      sc[t] = __builtin_amdgcn_mfma_f32_16x16x32_bf16(
          qfrag, kf, (f32x4){0.f, 0.f, 0.f, 0.f}, 0, 0, 0);
    }
#pragma unroll
    for (int r = 0; r < 4; ++r) {
      const float* bi = bbase + (size_t)(ibase + lg * 4 + r) * N_ + j0 + lr;
#pragma unroll
      for (int t = 0; t < 4; ++t)
        sc[t][r] = fmaf(sc[t][r], SCALE2_, bi[t * 16]);
    }
    float mt[4];
#pragma unroll
    for (int r = 0; r < 4; ++r)
      mt[r] = fmaxf(fmaxf(sc[0][r], sc[1][r]), fmaxf(sc[2][r], sc[3][r]));
#pragma unroll
    for (int off = 1; off < 16; off <<= 1)
#pragma unroll
      for (int r = 0; r < 4; ++r)
        mt[r] = fmaxf(mt[r], __shfl_xor(mt[r], off));
    float corr[4];
#pragma unroll
    for (int r = 0; r < 4; ++r) {
      float mn = fmaxf(m_run[r], mt[r]);
      corr[r] = exp2f(m_run[r] - mn);
      m_run[r] = mn;
    }
#pragma unroll
    for (int t = 0; t < 4; ++t)
#pragma unroll
      for (int r = 0; r < 4; ++r)
        sc[t][r] = exp2f(sc[t][r] - m_run[r]);
#pragma unroll
    for (int r = 0; r < 4; ++r) {
      acc[0][r] *= corr[r];
      acc[1][r] *= corr[r];
      accL[r]   *= corr[r];
    }
#pragma unroll
    for (int t = 0; t < 4; ++t)
#pragma unroll
      for (int r = 0; r < 4; ++r)
        p_lds[w][lg * 4 + r][t * 16 + lr] = f2bf(sc[t][r]);
#pragma unroll
    for (int kc = 0; kc < 2; ++kc) {
      short8 pf = *(const short8*)&p_lds[w][lr][kc * 32 + lg * 8];
#pragma unroll
      for (int c = 0; c < 2; ++c) {
        short8 vf = *(const short8*)(vb + (size_t)(c * 16 + lr) * N_ +
                                     j0 + kc * 32 + lg * 8);
        acc[c] = __builtin_amdgcn_mfma_f32_16x16x32_bf16(pf, vf, acc[c], 0, 0, 0);
      }
      accL = __builtin_amdgcn_mfma_f32_16x16x32_bf16(pf, ones8, accL, 0, 0, 0);
    }
  }

  if (jq > 0) {
#pragma unroll
    for (int c = 0; c < 2; ++c)
#pragma unroll
      for (int r = 0; r < 4; ++r)
        acc_lds[jq - 1][s][lg * 4 + r][c * 16 + lr] = acc[c][r];
    if (lr == 0) {
#pragma unroll
      for (int r = 0; r < 4; ++r) {
        ml_lds[jq - 1][s][lg * 4 + r][0] = m_run[r];
        ml_lds[jq - 1][s][lg * 4 + r][1] = accL[r];
      }
    }
  }
  __syncthreads();
  if (jq == 0) {
    float c0[4], cq[3][4], linv[4];
#pragma unroll
    for (int r = 0; r < 4; ++r) {
      int row = lg * 4 + r;
      float m = m_run[r];
#pragma unroll
      for (int q = 0; q < 3; ++q) m = fmaxf(m, ml_lds[q][s][row][0]);
      c0[r] = exp2f(m_run[r] - m);
      float lsum = accL[r] * c0[r];
#pragma unroll
      for (int q = 0; q < 3; ++q) {
        cq[q][r] = exp2f(ml_lds[q][s][row][0] - m);
        lsum = fmaf(ml_lds[q][s][row][1], cq[q][r], lsum);
      }
      linv[r] = 1.f / lsum;
    }
#pragma unroll
    for (int c = 0; c < 2; ++c) {
#pragma unroll
      for (int r = 0; r < 4; ++r) {
        int row = lg * 4 + r;
        int i = ibase + row;
        int d = c * 16 + lr;
        float o = acc[c][r] * c0[r];
#pragma unroll
        for (int q = 0; q < 3; ++q)
          o = fmaf(acc_lds[q][s][row][d], cq[q][r], o);
        o *= linv[r];
        size_t oidx = (size_t)(b * N_ + i) * D_ + h * DH_ + d;
        unsigned short hi = f2bf(o);
        ophi[oidx] = hi;
        oplo[oidx] = f2bf(o - bf2f(hi));
      }
    }
  }
}

// ---------------------------------------------------------------------------
extern "C" void kernel_launch(void* const* d_in, const int* in_sizes, int n_in,
                              void* d_out, int out_size, void* d_ws, size_t ws_size,
                              hipStream_t stream) {
  const float* src    = (const float*)d_in[0];
  const float* coords = (const float*)d_in[1];
  const float* Wq  = (const float*)d_in[2];
  const float* Wk  = (const float*)d_in[3];
  const float* Wv  = (const float*)d_in[4];
  const float* Wo  = (const float*)d_in[5];
  const float* gw1 = (const float*)d_in[6];
  const float* gb1 = (const float*)d_in[7];
  const float* gw2 = (const float*)d_in[8];
  const float* gb2 = (const float*)d_in[9];
  const float* dw1 = (const float*)d_in[10];
  const float* db1 = (const float*)d_in[11];
  const float* dw2 = (const float*)d_in[12];
  const float* db2 = (const float*)d_in[13];
  float* out = (float*)d_out;

  char* wsb = (char*)d_ws;
  unsigned short* qbf  = (unsigned short*)wsb;                        // 1 MB
  unsigned short* kbf  = (unsigned short*)(wsb + (1 << 20));          // 1 MB
  unsigned short* vtbf = (unsigned short*)(wsb + (2 << 20));          // 1 MB
  float* biasw         = (float*)(wsb + (3 << 20));                   // 8 MB
  unsigned short* whi  = (unsigned short*)(wsb + (11 << 20));         // 512 KB
  unsigned short* wlo  = (unsigned short*)(wsb + (11 << 20) + (512 << 10));
  unsigned short* shi  = (unsigned short*)(wsb + (12 << 20));         // 1 MB
  unsigned short* slo  = (unsigned short*)(wsb + (13 << 20));         // 1 MB
  unsigned short* ophi = (unsigned short*)(wsb + (14 << 20));         // 1 MB
  unsigned short* oplo = (unsigned short*)(wsb + (15 << 20));         // 1 MB

  bias_split_kernel<<<2240, 256, 0, stream>>>(coords, gw1, gb1, gw2, gb2,
                                              dw1, db1, dw2, db2, biasw,
                                              Wq, Wk, Wv, Wo, src,
                                              whi, wlo, shi, slo);
  qkv_kernel<<<dim3(32, 4, 3), 256, 0, stream>>>(shi, slo, whi, wlo, qbf, kbf, vtbf);
  attn_kernel<<<512, 512, 0, stream>>>(qbf, kbf, vtbf, biasw, ophi, oplo);
  projo_kernel<<<dim3(32, 4), 256, 0, stream>>>(ophi, oplo, whi, wlo, out);
}

// Round 12
// 79.610 us; speedup vs baseline: 3.0173x; 1.1296x over previous
//
#include <hip/hip_runtime.h>
#include <hip/hip_bf16.h>
#include <math.h>

constexpr int B_ = 2;
constexpr int N_ = 1024;
constexpr int D_ = 256;
constexpr int H_ = 8;
constexpr int DH_ = 32;
constexpr float SCALE_ = 0.17677669529663687f;  // 1/sqrt(32)
constexpr float LOG2E_ = 1.4426950408889634f;
constexpr float SCALE2_ = SCALE_ * LOG2E_;      // qk scale in exp2 domain
constexpr float EPSV_ = 1e-4f;

typedef __attribute__((ext_vector_type(8))) short short8;
typedef __attribute__((ext_vector_type(4))) float f32x4;

__device__ __forceinline__ unsigned short f2bf(float x) {
  __hip_bfloat16 h = __float2bfloat16(x);
  return __builtin_bit_cast(unsigned short, h);
}
__device__ __forceinline__ float bf2f(unsigned short u) {
  unsigned int x = ((unsigned int)u) << 16;
  return __builtin_bit_cast(float, x);
}

// Split 8 consecutive f32 into bf16 hi + bf16 lo (residual). Same function
// the old split_kernel used -> inline use is bitwise-identical to pre-split.
__device__ __forceinline__ void split8(const float* __restrict__ p,
                                       short8& hi, short8& lo) {
  f32x4 f0 = *(const f32x4*)p;
  f32x4 f1 = *(const f32x4*)(p + 4);
#pragma unroll
  for (int i = 0; i < 4; ++i) {
    unsigned short h0 = f2bf(f0[i]);
    hi[i] = (short)h0;
    lo[i] = (short)f2bf(f0[i] - bf2f(h0));
    unsigned short h1 = f2bf(f1[i]);
    hi[4 + i] = (short)h1;
    lo[4 + i] = (short)f2bf(f1[i] - bf2f(h1));
  }
}

__device__ __forceinline__ float lgamma_fast(float x) {
  float y = (x < 1.f) ? x : (x - 1.f);
  float g = fmaf(y, 0.035868343f, -0.193527818f);
  g = fmaf(y, g, 0.482199394f);
  g = fmaf(y, g, -0.756704078f);
  g = fmaf(y, g, 0.918206857f);
  g = fmaf(y, g, -0.897056937f);
  g = fmaf(y, g, 0.988205891f);
  g = fmaf(y, g, -0.577191652f);
  g = fmaf(y, g, 1.0f);
  float lg = __logf(g);
  return (x < 1.f) ? lg - __logf(x) : lg;
}
__device__ __forceinline__ float softplus_fast(float x) {
  return __logf(1.f + __expf(x));
}

// ---------------------------------------------------------------------------
// Split-bf16 MFMA GEMM wave body, INLINE split (r4 pattern, values bitwise
// identical to the pre-split tables). C[16 rows][64 cols] per wave.
// acc row = (l>>4)*4 + reg, col = ct*16 + (l&15)  [m89/m91 layout].
// ---------------------------------------------------------------------------
__device__ __forceinline__
void mfma_proj_wave_f32(const float* __restrict__ A, const float* __restrict__ W,
                        int r0, int c0, f32x4 (&acc)[4]) {
  const int l = threadIdx.x & 63;
  const int lr = l & 15, lg = l >> 4;
#pragma unroll
  for (int ct = 0; ct < 4; ++ct) acc[ct] = (f32x4){0.f, 0.f, 0.f, 0.f};
#pragma unroll 2
  for (int ks = 0; ks < 8; ++ks) {
    short8 ahi, alo;
    split8(A + (size_t)(r0 + lr) * D_ + ks * 32 + lg * 8, ahi, alo);
#pragma unroll
    for (int ct = 0; ct < 4; ++ct) {
      short8 wh, wl;
      split8(W + (size_t)(c0 + ct * 16 + lr) * D_ + ks * 32 + lg * 8, wh, wl);
      acc[ct] = __builtin_amdgcn_mfma_f32_16x16x32_bf16(ahi, wh, acc[ct], 0, 0, 0);
      acc[ct] = __builtin_amdgcn_mfma_f32_16x16x32_bf16(alo, wh, acc[ct], 0, 0, 0);
      acc[ct] = __builtin_amdgcn_mfma_f32_16x16x32_bf16(ahi, wl, acc[ct], 0, 0, 0);
    }
  }
}

// Pure-load variant for projo (A = attn output pre-split by attn epilogue).
__device__ __forceinline__
void mfma_wave_pure(const unsigned short* __restrict__ Ahi,
                    const unsigned short* __restrict__ Alo,
                    const unsigned short* __restrict__ whi,
                    const unsigned short* __restrict__ wlo,
                    int r0, int c0, f32x4 (&acc)[4]) {
  const int l = threadIdx.x & 63;
  const int lr = l & 15, lg = l >> 4;
#pragma unroll
  for (int ct = 0; ct < 4; ++ct) acc[ct] = (f32x4){0.f, 0.f, 0.f, 0.f};
#pragma unroll 2
  for (int ks = 0; ks < 8; ++ks) {
    size_t aoff = (size_t)(r0 + lr) * D_ + ks * 32 + lg * 8;
    short8 ahi = *(const short8*)(Ahi + aoff);
    short8 alo = *(const short8*)(Alo + aoff);
#pragma unroll
    for (int ct = 0; ct < 4; ++ct) {
      size_t woff = (size_t)(c0 + ct * 16 + lr) * D_ + ks * 32 + lg * 8;
      short8 wh = *(const short8*)(whi + woff);
      short8 wl = *(const short8*)(wlo + woff);
      acc[ct] = __builtin_amdgcn_mfma_f32_16x16x32_bf16(ahi, wh, acc[ct], 0, 0, 0);
      acc[ct] = __builtin_amdgcn_mfma_f32_16x16x32_bf16(alo, wh, acc[ct], 0, 0, 0);
      acc[ct] = __builtin_amdgcn_mfma_f32_16x16x32_bf16(ahi, wl, acc[ct], 0, 0, 0);
    }
  }
}

// ---------------------------------------------------------------------------
// K1: bias (blocks 0..2047, v6 body) + QKV with inline split (2048..2431)
// + Wo hi/lo split for projo (2432..2495). All three independent given raw
// inputs -> no barriers; block-range dispatch. 4->3 kernels tests the
// per-kernel-boundary-overhead hypothesis (r11 post-mortem).
// ---------------------------------------------------------------------------
__global__ __launch_bounds__(256)
void fused1_kernel(const float* __restrict__ coords,
                   const float* __restrict__ gw1, const float* __restrict__ gb1,
                   const float* __restrict__ gw2, const float* __restrict__ gb2,
                   const float* __restrict__ dw1, const float* __restrict__ db1,
                   const float* __restrict__ dw2, const float* __restrict__ db2,
                   float* __restrict__ bias,
                   const float* __restrict__ Wq, const float* __restrict__ Wk,
                   const float* __restrict__ Wv, const float* __restrict__ Wo,
                   const float* __restrict__ src,
                   unsigned short* __restrict__ whi, unsigned short* __restrict__ wlo,
                   unsigned short* __restrict__ qbf, unsigned short* __restrict__ kbf,
                   unsigned short* __restrict__ vtbf) {
  const int tid = threadIdx.x;
  const int bi = blockIdx.x;

  if (bi >= 2432) {  // ---- Wo split (64 blocks x 256 thr x 4 floats) ----
    int idx = ((bi - 2432) * 256 + tid) * 4;
    float4 f = *(const float4*)(Wo + idx);
    ushort4 hi, lo;
    hi.x = f2bf(f.x); lo.x = f2bf(f.x - bf2f(hi.x));
    hi.y = f2bf(f.y); lo.y = f2bf(f.y - bf2f(hi.y));
    hi.z = f2bf(f.z); lo.z = f2bf(f.z - bf2f(hi.z));
    hi.w = f2bf(f.w); lo.w = f2bf(f.w - bf2f(hi.w));
    *(ushort4*)(whi + 3 * 65536 + idx) = hi;
    *(ushort4*)(wlo + 3 * 65536 + idx) = lo;
    return;
  }

  if (bi >= 2048) {  // ---- QKV, inline split (384 blocks = old dim3(32,4,3)) --
    const int bi2 = bi - 2048;
    const int z = bi2 >> 7;
    const float* W = (z == 0) ? Wq : (z == 1) ? Wk : Wv;
    const int rem = bi2 & 127;
    const int by = rem >> 5, bx = rem & 31;
    const int w = tid >> 6;
    const int r0 = bx * 64 + w * 16;
    const int c0 = by * 64;
    f32x4 acc[4];
    mfma_proj_wave_f32(src, W, r0, c0, acc);

    const int l = tid & 63, lr = l & 15, lg = l >> 4;
    if (z < 2) {
      unsigned short* dst = (z == 0) ? qbf : kbf;
#pragma unroll
      for (int ct = 0; ct < 4; ++ct) {
        int o = c0 + ct * 16 + lr, h = o >> 5, d = o & 31;
#pragma unroll
        for (int r = 0; r < 4; ++r) {
          int R = r0 + lg * 4 + r, b = R >> 10, n = R & 1023;
          dst[(size_t)((b * H_ + h) * N_ + n) * DH_ + d] = f2bf(acc[ct][r]);
        }
      }
    } else {
#pragma unroll
      for (int ct = 0; ct < 4; ++ct) {
        int o = c0 + ct * 16 + lr, h = o >> 5, d = o & 31;
#pragma unroll
        for (int r = 0; r < 4; ++r) {
          int R = r0 + lg * 4 + r, b = R >> 10, n = R & 1023;
          vtbf[(size_t)((b * H_ + h) * DH_ + d) * N_ + n] = f2bf(acc[ct][r]);
        }
      }
    }
    return;
  }

  // ---- bias v6 body (4 pairs/thread, wave-uniform scalar weight reads) ----
  const int jt = bi & 3;
  const int it = (bi >> 2) & 255;
  const int b  = bi >> 10;
  const int j  = jt * 256 + tid;
  const int ibase = it * 4;

  const float4 cj = ((const float4*)coords)[b * N_ + j];

  float dist[4], dtv[4];
#pragma unroll
  for (int ii = 0; ii < 4; ++ii) {
    const float* cp = coords + 4 * (b * N_ + ibase + ii);  // uniform -> s_load
    float dx = cp[0] - cj.x, dy = cp[1] - cj.y, dz = cp[2] - cj.z;
    dist[ii] = sqrtf(dx * dx + dy * dy + dz * dz);
    dtv[ii]  = cp[3] - cj.w;
  }

  const float db20 = db2[0], db21 = db2[1], gb20 = gb2[0];
  float biasv[4], raw0[4], raw1[4];
#pragma unroll
  for (int ii = 0; ii < 4; ++ii) { biasv[ii] = 0.f; raw0[ii] = db20; raw1[ii] = db21; }

#pragma unroll 4
  for (int h = 0; h < 64; ++h) {
    float g0 = gw1[2 * h], g1 = gw1[2 * h + 1], gb = gb1[h], g2 = gw2[h];
    float w0 = dw1[4 * h], wx = dw1[4 * h + 1], wy = dw1[4 * h + 2], wz = dw1[4 * h + 3];
    float c0 = db1[h], c1 = dw2[h], c2 = dw2[64 + h];
    float dp = fmaf(wx, cj.x, fmaf(wy, cj.y, fmaf(wz, cj.z, c0)));
#pragma unroll
    for (int ii = 0; ii < 4; ++ii) {
      float g = fmaf(g0, dist[ii], fmaf(g1, dtv[ii], gb));
      biasv[ii] = fmaf(g2, fmaxf(g, 0.f), biasv[ii]);
      float dh_ = fmaxf(fmaf(w0, dist[ii], dp), 0.f);
      raw0[ii] = fmaf(c1, dh_, raw0[ii]);
      raw1[ii] = fmaf(c2, dh_, raw1[ii]);
    }
  }

#pragma unroll
  for (int ii = 0; ii < 4; ++ii) {
    float sh  = softplus_fast(raw0[ii]) + EPSV_;
    float ra  = softplus_fast(raw1[ii]) + EPSV_;
    float dtp = fmaxf(fabsf(dtv[ii]), EPSV_);
    float lp  = sh * __logf(ra) + (sh - 1.f) * __logf(dtp) - ra * dtp - lgamma_fast(sh);
    bias[(size_t)(b * N_ + ibase + ii) * N_ + j] = (biasv[ii] + gb20 + lp) * LOG2E_;
  }
}

// ---------------------------------------------------------------------------
// MFMA flash attention, 4-way split-j, exp2 domain (unchanged from r11).
// ---------------------------------------------------------------------------
__global__ __launch_bounds__(512)
void attn_kernel(const unsigned short* __restrict__ qbf,
                 const unsigned short* __restrict__ kbf,
                 const unsigned short* __restrict__ vtbf,
                 const float* __restrict__ biasg,
                 unsigned short* __restrict__ ophi,
                 unsigned short* __restrict__ oplo) {
  __shared__ __align__(16) unsigned short p_lds[8][16][72];
  __shared__ float acc_lds[3][2][16][32];
  __shared__ float ml_lds[3][2][16][2];

  const int tid = threadIdx.x;
  const int w = tid >> 6, l = tid & 63;
  const int s = w >> 2, jq = w & 3;
  const int lr = l & 15, lg = l >> 4;
  const int bh = blockIdx.x >> 5;
  const int qb = blockIdx.x & 31;
  const int b = bh >> 3, h = bh & 7;
  const int ibase = qb * 32 + s * 16;

  const short8 ones8 = {16256, 16256, 16256, 16256, 16256, 16256, 16256, 16256};

  const short8 qfrag =
      *(const short8*)(qbf + (size_t)(bh * N_ + ibase + lr) * DH_ + lg * 8);
  const unsigned short* kb = kbf + (size_t)bh * N_ * DH_;
  const unsigned short* vb = vtbf + (size_t)bh * DH_ * N_;
  const float* bbase = biasg + (size_t)b * N_ * N_;

  f32x4 acc[2], accL;
  acc[0] = (f32x4){0.f, 0.f, 0.f, 0.f};
  acc[1] = (f32x4){0.f, 0.f, 0.f, 0.f};
  accL   = (f32x4){0.f, 0.f, 0.f, 0.f};
  float m_run[4];
#pragma unroll
  for (int r = 0; r < 4; ++r) m_run[r] = -3e38f;

  const int jbeg = jq * 256;
  for (int j0 = jbeg; j0 < jbeg + 256; j0 += 64) {
    f32x4 sc[4];
#pragma unroll
    for (int t = 0; t < 4; ++t) {
      short8 kf = *(const short8*)(kb + (size_t)(j0 + t * 16 + lr) * DH_ + lg * 8);
      sc[t] = __builtin_amdgcn_mfma_f32_16x16x32_bf16(
          qfrag, kf, (f32x4){0.f, 0.f, 0.f, 0.f}, 0, 0, 0);
    }
#pragma unroll
    for (int r = 0; r < 4; ++r) {
      const float* bi = bbase + (size_t)(ibase + lg * 4 + r) * N_ + j0 + lr;
#pragma unroll
      for (int t = 0; t < 4; ++t)
        sc[t][r] = fmaf(sc[t][r], SCALE2_, bi[t * 16]);
    }
    float mt[4];
#pragma unroll
    for (int r = 0; r < 4; ++r)
      mt[r] = fmaxf(fmaxf(sc[0][r], sc[1][r]), fmaxf(sc[2][r], sc[3][r]));
#pragma unroll
    for (int off = 1; off < 16; off <<= 1)
#pragma unroll
      for (int r = 0; r < 4; ++r)
        mt[r] = fmaxf(mt[r], __shfl_xor(mt[r], off));
    float corr[4];
#pragma unroll
    for (int r = 0; r < 4; ++r) {
      float mn = fmaxf(m_run[r], mt[r]);
      corr[r] = exp2f(m_run[r] - mn);
      m_run[r] = mn;
    }
#pragma unroll
    for (int t = 0; t < 4; ++t)
#pragma unroll
      for (int r = 0; r < 4; ++r)
        sc[t][r] = exp2f(sc[t][r] - m_run[r]);
#pragma unroll
    for (int r = 0; r < 4; ++r) {
      acc[0][r] *= corr[r];
      acc[1][r] *= corr[r];
      accL[r]   *= corr[r];
    }
#pragma unroll
    for (int t = 0; t < 4; ++t)
#pragma unroll
      for (int r = 0; r < 4; ++r)
        p_lds[w][lg * 4 + r][t * 16 + lr] = f2bf(sc[t][r]);
#pragma unroll
    for (int kc = 0; kc < 2; ++kc) {
      short8 pf = *(const short8*)&p_lds[w][lr][kc * 32 + lg * 8];
#pragma unroll
      for (int c = 0; c < 2; ++c) {
        short8 vf = *(const short8*)(vb + (size_t)(c * 16 + lr) * N_ +
                                     j0 + kc * 32 + lg * 8);
        acc[c] = __builtin_amdgcn_mfma_f32_16x16x32_bf16(pf, vf, acc[c], 0, 0, 0);
      }
      accL = __builtin_amdgcn_mfma_f32_16x16x32_bf16(pf, ones8, accL, 0, 0, 0);
    }
  }

  if (jq > 0) {
#pragma unroll
    for (int c = 0; c < 2; ++c)
#pragma unroll
      for (int r = 0; r < 4; ++r)
        acc_lds[jq - 1][s][lg * 4 + r][c * 16 + lr] = acc[c][r];
    if (lr == 0) {
#pragma unroll
      for (int r = 0; r < 4; ++r) {
        ml_lds[jq - 1][s][lg * 4 + r][0] = m_run[r];
        ml_lds[jq - 1][s][lg * 4 + r][1] = accL[r];
      }
    }
  }
  __syncthreads();
  if (jq == 0) {
    float c0[4], cq[3][4], linv[4];
#pragma unroll
    for (int r = 0; r < 4; ++r) {
      int row = lg * 4 + r;
      float m = m_run[r];
#pragma unroll
      for (int q = 0; q < 3; ++q) m = fmaxf(m, ml_lds[q][s][row][0]);
      c0[r] = exp2f(m_run[r] - m);
      float lsum = accL[r] * c0[r];
#pragma unroll
      for (int q = 0; q < 3; ++q) {
        cq[q][r] = exp2f(ml_lds[q][s][row][0] - m);
        lsum = fmaf(ml_lds[q][s][row][1], cq[q][r], lsum);
      }
      linv[r] = 1.f / lsum;
    }
#pragma unroll
    for (int c = 0; c < 2; ++c) {
#pragma unroll
      for (int r = 0; r < 4; ++r) {
        int row = lg * 4 + r;
        int i = ibase + row;
        int d = c * 16 + lr;
        float o = acc[c][r] * c0[r];
#pragma unroll
        for (int q = 0; q < 3; ++q)
          o = fmaf(acc_lds[q][s][row][d], cq[q][r], o);
        o *= linv[r];
        size_t oidx = (size_t)(b * N_ + i) * D_ + h * DH_ + d;
        unsigned short hi = f2bf(o);
        ophi[oidx] = hi;
        oplo[oidx] = f2bf(o - bf2f(hi));
      }
    }
  }
}

// ---------------------------------------------------------------------------
// Output projection (unchanged from r11).
// ---------------------------------------------------------------------------
__global__ __launch_bounds__(256)
void projo_kernel(const unsigned short* __restrict__ ophi,
                  const unsigned short* __restrict__ oplo,
                  const unsigned short* __restrict__ whi,
                  const unsigned short* __restrict__ wlo,
                  float* __restrict__ out) {
  const int w = threadIdx.x >> 6;
  const int r0 = blockIdx.x * 64 + w * 16;
  const int c0 = blockIdx.y * 64;
  f32x4 acc[4];
  mfma_wave_pure(ophi, oplo, whi + 3 * 65536, wlo + 3 * 65536, r0, c0, acc);
  const int l = threadIdx.x & 63, lr = l & 15, lg = l >> 4;
#pragma unroll
  for (int ct = 0; ct < 4; ++ct)
#pragma unroll
    for (int r = 0; r < 4; ++r)
      out[(size_t)(r0 + lg * 4 + r) * D_ + c0 + ct * 16 + lr] = acc[ct][r];
}

// ---------------------------------------------------------------------------
extern "C" void kernel_launch(void* const* d_in, const int* in_sizes, int n_in,
                              void* d_out, int out_size, void* d_ws, size_t ws_size,
                              hipStream_t stream) {
  const float* src    = (const float*)d_in[0];
  const float* coords = (const float*)d_in[1];
  const float* Wq  = (const float*)d_in[2];
  const float* Wk  = (const float*)d_in[3];
  const float* Wv  = (const float*)d_in[4];
  const float* Wo  = (const float*)d_in[5];
  const float* gw1 = (const float*)d_in[6];
  const float* gb1 = (const float*)d_in[7];
  const float* gw2 = (const float*)d_in[8];
  const float* gb2 = (const float*)d_in[9];
  const float* dw1 = (const float*)d_in[10];
  const float* db1 = (const float*)d_in[11];
  const float* dw2 = (const float*)d_in[12];
  const float* db2 = (const float*)d_in[13];
  float* out = (float*)d_out;

  char* wsb = (char*)d_ws;
  unsigned short* qbf  = (unsigned short*)wsb;                        // 1 MB
  unsigned short* kbf  = (unsigned short*)(wsb + (1 << 20));          // 1 MB
  unsigned short* vtbf = (unsigned short*)(wsb + (2 << 20));          // 1 MB
  float* biasw         = (float*)(wsb + (3 << 20));                   // 8 MB
  unsigned short* whi  = (unsigned short*)(wsb + (11 << 20));         // 512 KB
  unsigned short* wlo  = (unsigned short*)(wsb + (11 << 20) + (512 << 10));
  unsigned short* ophi = (unsigned short*)(wsb + (14 << 20));         // 1 MB
  unsigned short* oplo = (unsigned short*)(wsb + (15 << 20));         // 1 MB

  fused1_kernel<<<2496, 256, 0, stream>>>(coords, gw1, gb1, gw2, gb2,
                                          dw1, db1, dw2, db2, biasw,
                                          Wq, Wk, Wv, Wo, src,
                                          whi, wlo, qbf, kbf, vtbf);
  attn_kernel<<<512, 512, 0, stream>>>(qbf, kbf, vtbf, biasw, ophi, oplo);
  projo_kernel<<<dim3(32, 4), 256, 0, stream>>>(ophi, oplo, whi, wlo, out);
}